// Round 6
// baseline (255.311 us; speedup 1.0000x reference)
//
#include <hip/hip_runtime.h>

#define T_ 1024
#define B_ 4
#define D_ 1024
#define H_ 16
#define HD_ 64
#define M_ (T_ * B_)  // 4096

typedef _Float16 f16;
typedef f16 f16x8 __attribute__((ext_vector_type(8)));
typedef f16 f16x4 __attribute__((ext_vector_type(4)));
typedef float f32x4 __attribute__((ext_vector_type(4)));

__device__ __forceinline__ void gl2lds16(const void* g, void* l) {
  __builtin_amdgcn_global_load_lds(
      (const __attribute__((address_space(1))) void*)g,
      (__attribute__((address_space(3))) void*)l, 16, 0, 0);
}

// ---------------------------------------------------------------- cvt fp32->fp16
__global__ __launch_bounds__(256) void cvt_f32_f16(const float* __restrict__ in,
                                                   f16* __restrict__ out, int n) {
  int i = (blockIdx.x * 256 + threadIdx.x) * 4;
  if (i >= n) return;
  float4 v = *(const float4*)(in + i);
  f16x4 o = {(f16)v.x, (f16)v.y, (f16)v.z, (f16)v.w};
  *(f16x4*)(out + i) = o;
}

struct WPtrs {
  const float* s[5];
  f16* d[5];
};

// all 5 weight matrices (1M elems each) in one launch: blockIdx>>10 = which
__global__ __launch_bounds__(256) void cvt5(WPtrs p) {
  const int a = blockIdx.x >> 10;
  const int i = ((blockIdx.x & 1023) * 256 + threadIdx.x) * 4;
  float4 v = *(const float4*)(p.s[a] + i);
  f16x4 o = {(f16)v.x, (f16)v.y, (f16)v.z, (f16)v.w};
  *(f16x4*)(p.d[a] + i) = o;
}

// concat 3 bias vectors (1024 each) into bqkv[3072]
__global__ __launch_bounds__(256) void bcat(const float* __restrict__ b0,
                                            const float* __restrict__ b1,
                                            const float* __restrict__ b2,
                                            float* __restrict__ dst) {
  const float* src = blockIdx.x == 0 ? b0 : (blockIdx.x == 1 ? b1 : b2);
  const int i = threadIdx.x * 4;
  *(float4*)(dst + blockIdx.x * 1024 + i) = *(const float4*)(src + i);
}

// LDS layout for BK=64 tiles: chunk index (row*8 + p) holds global k-chunk
// p^(row&7) (16B chunks). Read row r, k-chunk g at: r*64 + ((g^(r&7))*8).
// Bank math: for fixed g, 8 consecutive rows map chunks to 8 distinct bank
// quads -> conflict-free b128 reads.

// ---------------------------------------------------------------- GEMM 128x64 (BK=64)
// out[M,N] = A @ W^T + bias + res; 512 blocks -> 2 blocks/CU.
__global__ __launch_bounds__(256) void gemm_f16(const f16* __restrict__ A,
                                                const f16* __restrict__ W,
                                                const float* __restrict__ bias,
                                                const float* __restrict__ res,
                                                float* __restrict__ out) {
  constexpr int K = D_, BK = 64;
  __shared__ __align__(16) f16 As[128 * BK];  // 16KB
  __shared__ __align__(16) f16 Bs[64 * BK];   // 8KB
  const int tid = threadIdx.x;
  const int lane = tid & 63;
  const int quad = lane >> 4, l16 = lane & 15;
  const int m0 = blockIdx.y * 128, n0 = blockIdx.x * 64;
  const int wave = tid >> 6;
  const int wm = (wave >> 1) * 64, wn = (wave & 1) * 32;
  f32x4 acc[4][2] = {};
  for (int kt = 0; kt < K / BK; ++kt) {
    __syncthreads();
    const int kb = kt * BK;
#pragma unroll
    for (int i = 0; i < 4; ++i) {  // A-tile: 1024 chunks
      const int c = i * 256 + tid;
      const int row = c >> 3, p = c & 7, g = p ^ (row & 7);
      gl2lds16(A + (size_t)(m0 + row) * K + kb + g * 8,
               &As[(i * 256 + (tid & ~63)) * 8]);
    }
#pragma unroll
    for (int i = 0; i < 2; ++i) {  // B-tile: 512 chunks
      const int c = i * 256 + tid;
      const int row = c >> 3, p = c & 7, g = p ^ (row & 7);
      gl2lds16(W + (size_t)(n0 + row) * K + kb + g * 8,
               &Bs[(i * 256 + (tid & ~63)) * 8]);
    }
    __syncthreads();
#pragma unroll
    for (int h = 0; h < 2; ++h) {  // two half-K passes, 16 MFMA each
      f16x8 af[4], bf[2];
#pragma unroll
      for (int i = 0; i < 4; ++i) {
        const int r = wm + i * 16 + l16;
        af[i] = *(const f16x8*)&As[r * 64 + (((h * 4 + quad) ^ (r & 7)) * 8)];
      }
#pragma unroll
      for (int j = 0; j < 2; ++j) {
        const int r = wn + j * 16 + l16;
        bf[j] = *(const f16x8*)&Bs[r * 64 + (((h * 4 + quad) ^ (r & 7)) * 8)];
      }
#pragma unroll
      for (int i = 0; i < 4; ++i)
#pragma unroll
        for (int j = 0; j < 2; ++j)
          acc[i][j] = __builtin_amdgcn_mfma_f32_16x16x32_f16(af[i], bf[j], acc[i][j], 0, 0, 0);
    }
  }
#pragma unroll
  for (int j = 0; j < 2; ++j) {
    const int n = n0 + wn + j * 16 + l16;
    const float bn = bias[n];
#pragma unroll
    for (int i = 0; i < 4; ++i) {
      const int m = m0 + wm + i * 16 + quad * 4;
#pragma unroll
      for (int r = 0; r < 4; ++r)
        out[(size_t)(m + r) * D_ + n] = acc[i][j][r] + bn + res[(size_t)(m + r) * D_ + n];
    }
  }
}

// ---------------------------------------------------------------- fused QKV GEMM (BK=64)
// W = [3072, K] (q,k,v stacked); q (pre-scaled by 0.125*log2e), k -> [B,H,T,HD];
// v -> [B,H,HD,T]
#define QSCALE 0.18033688011112042f  // 0.125 * log2(e), folded into q
__global__ __launch_bounds__(256) void gemm_qkv(const f16* __restrict__ A,
                                                const f16* __restrict__ W,
                                                const float* __restrict__ bias,
                                                f16* __restrict__ qo,
                                                f16* __restrict__ ko,
                                                f16* __restrict__ vo) {
  constexpr int K = D_, BK = 64;
  __shared__ __align__(16) f16 As[128 * BK];  // 16KB
  __shared__ __align__(16) f16 Bs[128 * BK];  // 16KB
  const int tid = threadIdx.x;
  const int lane = tid & 63;
  const int quad = lane >> 4, l16 = lane & 15;
  const int m0 = blockIdx.y * 128, n0 = blockIdx.x * 128;
  const int wave = tid >> 6;
  const int wm = (wave >> 1) * 64, wn = (wave & 1) * 64;
  f32x4 acc[4][4] = {};
  for (int kt = 0; kt < K / BK; ++kt) {
    __syncthreads();
    const int kb = kt * BK;
#pragma unroll
    for (int i = 0; i < 4; ++i) {  // 1024 chunks each
      const int c = i * 256 + tid;
      const int row = c >> 3, p = c & 7, g = p ^ (row & 7);
      const int ldsb = (i * 256 + (tid & ~63)) * 8;
      gl2lds16(A + (size_t)(m0 + row) * K + kb + g * 8, &As[ldsb]);
      gl2lds16(W + (size_t)(n0 + row) * K + kb + g * 8, &Bs[ldsb]);
    }
    __syncthreads();
#pragma unroll
    for (int h = 0; h < 2; ++h) {  // two half-K passes, 16 MFMA each
      f16x8 af[4], bf[4];
#pragma unroll
      for (int i = 0; i < 4; ++i) {
        const int r = wm + i * 16 + l16;
        af[i] = *(const f16x8*)&As[r * 64 + (((h * 4 + quad) ^ (r & 7)) * 8)];
      }
#pragma unroll
      for (int j = 0; j < 4; ++j) {
        const int r = wn + j * 16 + l16;
        bf[j] = *(const f16x8*)&Bs[r * 64 + (((h * 4 + quad) ^ (r & 7)) * 8)];
      }
#pragma unroll
      for (int i = 0; i < 4; ++i)
#pragma unroll
        for (int j = 0; j < 4; ++j)
          acc[i][j] = __builtin_amdgcn_mfma_f32_16x16x32_f16(af[i], bf[j], acc[i][j], 0, 0, 0);
    }
  }
  const int which = n0 >> 10;  // block-uniform: 0=q 1=k 2=v
  f16* outp = which == 0 ? qo : (which == 1 ? ko : vo);
  const float sc = which == 0 ? QSCALE : 1.0f;
#pragma unroll
  for (int j = 0; j < 4; ++j) {
    const int n = n0 + wn + j * 16 + l16;
    const float bn = bias[n];
    const int nl = n & 1023;
    const int hh = nl >> 6, d = nl & 63;
#pragma unroll
    for (int i = 0; i < 4; ++i) {
#pragma unroll
      for (int r = 0; r < 4; ++r) {
        const int m = m0 + wm + i * 16 + quad * 4 + r;
        const float v = (acc[i][j][r] + bn) * sc;
        const int t = m >> 2, bb = m & 3;  // m = t*B + b
        if (which < 2)
          outp[((size_t)(bb * H_ + hh) * T_ + t) * HD_ + d] = (f16)v;
        else
          outp[((size_t)(bb * H_ + hh) * HD_ + d) * T_ + t] = (f16)v;
      }
    }
  }
}

// ---------------------------------------------------------------- attention
// Flash-style, no max subtraction (scores pre-scaled so p=exp2(s), |s| small).
// Q-tile 128 rows/block, 32 per wave. Grid (bh, qi): all 8 qi-blocks of one
// bh land on one XCD (flat%8 = bh%8) so K/V stay L2-resident (2MB/XCD).
// Q,K: [B,H,T,HD] fp16; V: [B,H,HD,T] fp16; ctx out: [T*B, D] fp16
__global__ __launch_bounds__(256) void attn(const f16* __restrict__ Q,
                                            const f16* __restrict__ Km,
                                            const f16* __restrict__ Vt,
                                            f16* __restrict__ ctx) {
  constexpr int SK = 128;      // keys per tile
  constexpr int NT = T_ / SK;  // 8 tiles
  __shared__ __align__(16) f16 Ks[SK * HD_];    // 16KB, xor-swizzled chunks
  __shared__ __align__(16) f16 Vs[HD_ * SK];    // 16KB, xor-swizzled chunks
  __shared__ __align__(16) f16 Ps[4][16 * 36];  // per-wave P^T relayout buffer
  const int tid = threadIdx.x, wave = tid >> 6, lane = tid & 63;
  const int quad = lane >> 4, l16 = lane & 15;
  const int bh = blockIdx.x;           // b*H + h
  const int b = bh >> 4, h = bh & 15;
  const int q0 = blockIdx.y * 128;
  const f16* Qbh = Q + ((size_t)bh * T_ + q0 + wave * 32) * HD_;
  const f16* Kbh = Km + (size_t)bh * T_ * HD_;
  const f16* Vbh = Vt + (size_t)bh * HD_ * T_;

  // persistent Q fragments (B-operand), two 16-row column blocks per wave
  f16x8 qf[2][2];
#pragma unroll
  for (int c = 0; c < 2; ++c) {
    qf[c][0] = *(const f16x8*)&Qbh[(c * 16 + l16) * HD_ + quad * 8];
    qf[c][1] = *(const f16x8*)&Qbh[(c * 16 + l16) * HD_ + 32 + quad * 8];
  }

  // hoisted per-lane staging pointers (advance by constant stride per tile)
  const f16* kq[4];
  const f16* vq[4];
  int lds_o[4];
#pragma unroll
  for (int it = 0; it < 4; ++it) {
    const int n = wave * 256 + it * 64 + lane;
    const int s = n >> 3, cp = n & 7, cl = cp ^ (s & 7);
    kq[it] = Kbh + (size_t)s * HD_ + cl * 8;
    const int d = n >> 4, cp2 = n & 15, cl2 = cp2 ^ (d & 7);
    vq[it] = Vbh + (size_t)d * T_ + cl2 * 8;
    lds_o[it] = (wave * 256 + it * 64) * 8;
  }

  f32x4 O[4][2] = {};      // ctx^T acc: [d-tile][q colblock]
  float lsum[2] = {0.f, 0.f};
  const int sw = l16 & 7;  // xor-swizzle key

  for (int kt = 0; kt < NT; ++kt) {
    __syncthreads();
#pragma unroll
    for (int it = 0; it < 4; ++it) {
      gl2lds16(kq[it], &Ks[lds_o[it]]);
      kq[it] += SK * HD_;
    }
#pragma unroll
    for (int it = 0; it < 4; ++it) {
      gl2lds16(vq[it], &Vs[lds_o[it]]);
      vq[it] += SK;
    }
    __syncthreads();

    // S^T = K Q^T: 8 key subtiles x 2 q colblocks; p = exp2(s) immediately
    float st[8][2][4];
#pragma unroll
    for (int s = 0; s < 8; ++s) {
      const int row = s * 16 + l16;
      const f16x8 ka = *(const f16x8*)&Ks[row * HD_ + (quad ^ sw) * 8];
      const f16x8 kb = *(const f16x8*)&Ks[row * HD_ + ((4 + quad) ^ sw) * 8];
#pragma unroll
      for (int c = 0; c < 2; ++c) {
        f32x4 a = {};
        a = __builtin_amdgcn_mfma_f32_16x16x32_f16(ka, qf[c][0], a, 0, 0, 0);
        a = __builtin_amdgcn_mfma_f32_16x16x32_f16(kb, qf[c][1], a, 0, 0, 0);
#pragma unroll
        for (int r = 0; r < 4; ++r) {
          st[s][c][r] = exp2f(a[r]);
          lsum[c] += st[s][c][r];
        }
      }
    }

    // PV: 4 chunks of 32 keys; P^T -> B-frag via per-wave LDS relayout
#pragma unroll
    for (int cI = 0; cI < 4; ++cI) {
#pragma unroll
      for (int c = 0; c < 2; ++c) {
        f16* pw = &Ps[wave][0];
        f16x4 w0, w1;
#pragma unroll
        for (int r = 0; r < 4; ++r) {
          w0[r] = (f16)st[2 * cI][c][r];
          w1[r] = (f16)st[2 * cI + 1][c][r];
        }
        *(f16x4*)&pw[l16 * 36 + quad * 4] = w0;       // key_local = quad*4..+3
        *(f16x4*)&pw[l16 * 36 + 16 + quad * 4] = w1;  // key_local = 16+quad*4..+3
        const f16x8 pf = *(const f16x8*)&pw[l16 * 36 + quad * 8];
#pragma unroll
        for (int dt = 0; dt < 4; ++dt) {
          const int d = dt * 16 + l16;
          const f16x8 vf = *(const f16x8*)&Vs[d * SK + (((cI * 4 + quad) ^ sw) * 8)];
          O[dt][c] = __builtin_amdgcn_mfma_f32_16x16x32_f16(vf, pf, O[dt][c], 0, 0, 0);
        }
      }
    }
  }

  // reduce softmax denom across quads; normalize; store
#pragma unroll
  for (int c = 0; c < 2; ++c) {
    float l = lsum[c];
    l += __shfl_xor(l, 16, 64);
    l += __shfl_xor(l, 32, 64);
    const float linv = 1.f / l;
    const int t = q0 + wave * 32 + c * 16 + l16;
#pragma unroll
    for (int dt = 0; dt < 4; ++dt) {
      f16x4 ov;
#pragma unroll
      for (int r = 0; r < 4; ++r) ov[r] = (f16)(O[dt][c][r] * linv);
      *(f16x4*)&ctx[((size_t)t * B_ + b) * D_ + h * HD_ + dt * 16 + quad * 4] = ov;
    }
  }
}

// ---------------------------------------------------------------- LayerNorm (input already has residual)
__global__ __launch_bounds__(256) void lnorm(const float* __restrict__ a,
                                             const float* __restrict__ g,
                                             const float* __restrict__ bb,
                                             float* __restrict__ out,
                                             f16* __restrict__ outh) {
  const int row = blockIdx.x, tid = threadIdx.x;
  const size_t base = (size_t)row * D_;
  float4 va = *(const float4*)&a[base + tid * 4];
  float x0 = va.x, x1 = va.y, x2 = va.z, x3 = va.w;
  float s = x0 + x1 + x2 + x3;
  float sq = x0 * x0 + x1 * x1 + x2 * x2 + x3 * x3;
#pragma unroll
  for (int off = 32; off; off >>= 1) {
    s += __shfl_down(s, off, 64);
    sq += __shfl_down(sq, off, 64);
  }
  __shared__ float rs[4], rq[4];
  __shared__ float mean_s, rstd_s;
  if ((tid & 63) == 0) { rs[tid >> 6] = s; rq[tid >> 6] = sq; }
  __syncthreads();
  if (tid == 0) {
    float S = rs[0] + rs[1] + rs[2] + rs[3];
    float Qq = rq[0] + rq[1] + rq[2] + rq[3];
    float mean = S / D_;
    float var = Qq / D_ - mean * mean;
    mean_s = mean;
    rstd_s = rsqrtf(var + 1e-5f);
  }
  __syncthreads();
  const float mean = mean_s, rstd = rstd_s;
  float4 vg = *(const float4*)&g[tid * 4];
  float4 vb = *(const float4*)&bb[tid * 4];
  float y0 = (x0 - mean) * rstd * vg.x + vb.x;
  float y1 = (x1 - mean) * rstd * vg.y + vb.y;
  float y2 = (x2 - mean) * rstd * vg.z + vb.z;
  float y3 = (x3 - mean) * rstd * vg.w + vb.w;
  *(float4*)&out[base + tid * 4] = make_float4(y0, y1, y2, y3);
  if (outh) {
    f16x4 o = {(f16)y0, (f16)y1, (f16)y2, (f16)y3};
    *(f16x4*)&outh[base + tid * 4] = o;
  }
}

// ---------------------------------------------------------------- launch
extern "C" void kernel_launch(void* const* d_in, const int* in_sizes, int n_in,
                              void* d_out, int out_size, void* d_ws, size_t ws_size,
                              hipStream_t stream) {
  const float* x  = (const float*)d_in[0];
  const float* Wq = (const float*)d_in[1];
  const float* bq = (const float*)d_in[2];
  const float* Wk = (const float*)d_in[3];
  const float* bk = (const float*)d_in[4];
  const float* Wv = (const float*)d_in[5];
  const float* bv = (const float*)d_in[6];
  const float* Wo = (const float*)d_in[7];
  const float* bo = (const float*)d_in[8];
  const float* Wl = (const float*)d_in[9];
  const float* bl = (const float*)d_in[10];
  const float* g1 = (const float*)d_in[11];
  const float* b1 = (const float*)d_in[12];
  const float* g2 = (const float*)d_in[13];
  const float* b2 = (const float*)d_in[14];

  char* ws = (char*)d_ws;
  const size_t MB = 1 << 20;
  f16*   xb   = (f16*)(ws + 0 * MB);
  f16*   wqkv = (f16*)(ws + 8 * MB);
  f16*   wob  = (f16*)(ws + 14 * MB);
  f16*   wlb  = (f16*)(ws + 16 * MB);
  float* bqkv = (float*)(ws + 18 * MB);
  f16*   qb   = (f16*)(ws + 19 * MB);
  f16*   kb   = (f16*)(ws + 27 * MB);
  f16*   vb   = (f16*)(ws + 35 * MB);
  f16*   ctxb = xb;
  float* att  = (float*)qb;          // 16MB spanning qb+kb
  f16*   hb   = vb;
  float* hbuf = (float*)ws;          // 16MB spanning xb+wqkv+wob (all dead by then)

  cvt_f32_f16<<<M_ * D_ / 1024, 256, 0, stream>>>(x, xb, M_ * D_);
  WPtrs wp;
  wp.s[0] = Wq; wp.s[1] = Wk; wp.s[2] = Wv; wp.s[3] = Wo; wp.s[4] = Wl;
  wp.d[0] = wqkv; wp.d[1] = wqkv + D_ * D_; wp.d[2] = wqkv + 2 * D_ * D_;
  wp.d[3] = wob; wp.d[4] = wlb;
  cvt5<<<5 * 1024, 256, 0, stream>>>(wp);
  bcat<<<3, 256, 0, stream>>>(bq, bk, bv, bqkv);

  gemm_qkv<<<dim3(3 * D_ / 128, M_ / 128), 256, 0, stream>>>(xb, wqkv, bqkv, qb, kb, vb);

  attn<<<dim3(B_ * H_, T_ / 128), 256, 0, stream>>>(qb, kb, vb, ctxb);

  dim3 gg(D_ / 64, M_ / 128);  // (16, 32) = 512 blocks, 2/CU
  // Wo GEMM with fused residual (+x)
  gemm_f16<<<gg, 256, 0, stream>>>(ctxb, wob, bo, x, att);
  lnorm<<<M_, 256, 0, stream>>>(att, g1, b1, hbuf, hb);
  // Wl GEMM with fused residual (+h)
  gemm_f16<<<gg, 256, 0, stream>>>(hb, wlb, bl, hbuf, att);
  lnorm<<<M_, 256, 0, stream>>>(att, g2, b2, (float*)d_out, nullptr);
}

// Round 7
// 250.433 us; speedup vs baseline: 1.0195x; 1.0195x over previous
//
#include <hip/hip_runtime.h>

#define T_ 1024
#define B_ 4
#define D_ 1024
#define H_ 16
#define HD_ 64
#define M_ (T_ * B_)  // 4096

typedef _Float16 f16;
typedef f16 f16x8 __attribute__((ext_vector_type(8)));
typedef f16 f16x4 __attribute__((ext_vector_type(4)));
typedef float f32x4 __attribute__((ext_vector_type(4)));

__device__ __forceinline__ void gl2lds16(const void* g, void* l) {
  __builtin_amdgcn_global_load_lds(
      (const __attribute__((address_space(1))) void*)g,
      (__attribute__((address_space(3))) void*)l, 16, 0, 0);
}

// ---------------------------------------------------------------- cvt fp32->fp16
__global__ __launch_bounds__(256) void cvt_f32_f16(const float* __restrict__ in,
                                                   f16* __restrict__ out, int n) {
  int i = (blockIdx.x * 256 + threadIdx.x) * 4;
  if (i >= n) return;
  float4 v = *(const float4*)(in + i);
  f16x4 o = {(f16)v.x, (f16)v.y, (f16)v.z, (f16)v.w};
  *(f16x4*)(out + i) = o;
}

struct WPtrs {
  const float* s[5];
  f16* d[5];
};

// all 5 weight matrices (1M elems each) in one launch: blockIdx>>10 = which
__global__ __launch_bounds__(256) void cvt5(WPtrs p) {
  const int a = blockIdx.x >> 10;
  const int i = ((blockIdx.x & 1023) * 256 + threadIdx.x) * 4;
  float4 v = *(const float4*)(p.s[a] + i);
  f16x4 o = {(f16)v.x, (f16)v.y, (f16)v.z, (f16)v.w};
  *(f16x4*)(p.d[a] + i) = o;
}

// concat 3 bias vectors (1024 each) into bqkv[3072]
__global__ __launch_bounds__(256) void bcat(const float* __restrict__ b0,
                                            const float* __restrict__ b1,
                                            const float* __restrict__ b2,
                                            float* __restrict__ dst) {
  const float* src = blockIdx.x == 0 ? b0 : (blockIdx.x == 1 ? b1 : b2);
  const int i = threadIdx.x * 4;
  *(float4*)(dst + blockIdx.x * 1024 + i) = *(const float4*)(src + i);
}

// ---------------------------------------------------------------- GEMM 128x64 (BK=32)
// out[M,N] = A @ W^T + bias + res; 512 blocks -> 2 blocks/CU for barrier overlap.
__global__ __launch_bounds__(256) void gemm_f16(const f16* __restrict__ A,
                                                const f16* __restrict__ W,
                                                const float* __restrict__ bias,
                                                const float* __restrict__ res,
                                                float* __restrict__ out) {
  constexpr int K = D_, BK = 32;
  __shared__ __align__(16) f16 As[128 * BK];
  __shared__ __align__(16) f16 Bs[64 * BK];
  const int tid = threadIdx.x;
  const int lane = tid & 63;
  const int quad = lane >> 4, l16 = lane & 15;
  const int m0 = blockIdx.y * 128, n0 = blockIdx.x * 64;
  const int wave = tid >> 6;
  const int wm = (wave >> 1) * 64, wn = (wave & 1) * 32;
  f32x4 acc[4][2] = {};
  for (int kt = 0; kt < K / BK; ++kt) {
    __syncthreads();
    const int kb = kt * BK;
#pragma unroll
    for (int i = 0; i < 2; ++i) {  // A-tile: 512 x 16B chunks
      const int c = i * 256 + tid;
      const int row = c >> 2, col8 = (c & 3) * 8;
      const int ldsbase = (i * 256 + (tid & ~63)) * 8;
      gl2lds16(A + (size_t)(m0 + row) * K + kb + col8, &As[ldsbase]);
    }
    {  // B-tile: 256 x 16B chunks
      const int row = tid >> 2, col8 = (tid & 3) * 8;
      const int ldsbase = (tid & ~63) * 8;
      gl2lds16(W + (size_t)(n0 + row) * K + kb + col8, &Bs[ldsbase]);
    }
    __syncthreads();
    f16x8 af[4], bf[2];
#pragma unroll
    for (int i = 0; i < 4; ++i)
      af[i] = *(const f16x8*)&As[(wm + i * 16 + l16) * BK + quad * 8];
#pragma unroll
    for (int j = 0; j < 2; ++j)
      bf[j] = *(const f16x8*)&Bs[(wn + j * 16 + l16) * BK + quad * 8];
#pragma unroll
    for (int i = 0; i < 4; ++i)
#pragma unroll
      for (int j = 0; j < 2; ++j)
        acc[i][j] = __builtin_amdgcn_mfma_f32_16x16x32_f16(af[i], bf[j], acc[i][j], 0, 0, 0);
  }
#pragma unroll
  for (int j = 0; j < 2; ++j) {
    const int n = n0 + wn + j * 16 + l16;
    const float bn = bias[n];
#pragma unroll
    for (int i = 0; i < 4; ++i) {
      const int m = m0 + wm + i * 16 + quad * 4;
#pragma unroll
      for (int r = 0; r < 4; ++r)
        out[(size_t)(m + r) * D_ + n] = acc[i][j][r] + bn + res[(size_t)(m + r) * D_ + n];
    }
  }
}

// ---------------------------------------------------------------- fused QKV GEMM (BK=32)
// W = [3072, K] (q,k,v stacked); q (pre-scaled by 0.125*log2e), k -> [B,H,T,HD];
// v -> [B,H,HD,T]
#define QSCALE 0.18033688011112042f  // 0.125 * log2(e), folded into q
__global__ __launch_bounds__(256) void gemm_qkv(const f16* __restrict__ A,
                                                const f16* __restrict__ W,
                                                const float* __restrict__ bias,
                                                f16* __restrict__ qo,
                                                f16* __restrict__ ko,
                                                f16* __restrict__ vo) {
  constexpr int K = D_, BK = 32;
  __shared__ __align__(16) f16 As[128 * BK];
  __shared__ __align__(16) f16 Bs[128 * BK];
  const int tid = threadIdx.x;
  const int lane = tid & 63;
  const int quad = lane >> 4, l16 = lane & 15;
  const int m0 = blockIdx.y * 128, n0 = blockIdx.x * 128;
  const int wave = tid >> 6;
  const int wm = (wave >> 1) * 64, wn = (wave & 1) * 64;
  f32x4 acc[4][4] = {};
  for (int kt = 0; kt < K / BK; ++kt) {
    __syncthreads();
    const int kb = kt * BK;
#pragma unroll
    for (int i = 0; i < 2; ++i) {
      const int c = i * 256 + tid;
      const int row = c >> 2, col8 = (c & 3) * 8;
      const int ldsbase = (i * 256 + (tid & ~63)) * 8;
      gl2lds16(A + (size_t)(m0 + row) * K + kb + col8, &As[ldsbase]);
      gl2lds16(W + (size_t)(n0 + row) * K + kb + col8, &Bs[ldsbase]);
    }
    __syncthreads();
    f16x8 af[4], bf[4];
#pragma unroll
    for (int i = 0; i < 4; ++i)
      af[i] = *(const f16x8*)&As[(wm + i * 16 + l16) * BK + quad * 8];
#pragma unroll
    for (int j = 0; j < 4; ++j)
      bf[j] = *(const f16x8*)&Bs[(wn + j * 16 + l16) * BK + quad * 8];
#pragma unroll
    for (int i = 0; i < 4; ++i)
#pragma unroll
      for (int j = 0; j < 4; ++j)
        acc[i][j] = __builtin_amdgcn_mfma_f32_16x16x32_f16(af[i], bf[j], acc[i][j], 0, 0, 0);
  }
  const int which = n0 >> 10;  // block-uniform: 0=q 1=k 2=v
  f16* outp = which == 0 ? qo : (which == 1 ? ko : vo);
  const float sc = which == 0 ? QSCALE : 1.0f;
#pragma unroll
  for (int j = 0; j < 4; ++j) {
    const int n = n0 + wn + j * 16 + l16;
    const float bn = bias[n];
    const int nl = n & 1023;
    const int hh = nl >> 6, d = nl & 63;
#pragma unroll
    for (int i = 0; i < 4; ++i) {
#pragma unroll
      for (int r = 0; r < 4; ++r) {
        const int m = m0 + wm + i * 16 + quad * 4 + r;
        const float v = (acc[i][j][r] + bn) * sc;
        const int t = m >> 2, bb = m & 3;  // m = t*B + b
        if (which < 2)
          outp[((size_t)(bb * H_ + hh) * T_ + t) * HD_ + d] = (f16)v;
        else
          outp[((size_t)(bb * H_ + hh) * HD_ + d) * T_ + t] = (f16)v;
      }
    }
  }
}

// ---------------------------------------------------------------- attention
// Flash-style, no max subtraction (scores pre-scaled so p=exp2(s), |s| small).
// Q-tile 128 rows/block, 32 per wave. Grid (bh, qi): all 8 qi-blocks of one
// bh land on one XCD (flat%8 = bh%8) so K/V stay L2-resident (2MB/XCD).
// Q,K: [B,H,T,HD] fp16; V: [B,H,HD,T] fp16; ctx out: [T*B, D] fp16
__global__ __launch_bounds__(256) void attn(const f16* __restrict__ Q,
                                            const f16* __restrict__ Km,
                                            const f16* __restrict__ Vt,
                                            f16* __restrict__ ctx) {
  constexpr int SK = 128;      // keys per tile
  constexpr int NT = T_ / SK;  // 8 tiles
  __shared__ __align__(16) f16 Ks[SK * HD_];    // 16KB, xor-swizzled chunks
  __shared__ __align__(16) f16 Vs[HD_ * SK];    // 16KB, xor-swizzled chunks
  __shared__ __align__(16) f16 Ps[4][16 * 36];  // per-wave P^T relayout buffer
  const int tid = threadIdx.x, wave = tid >> 6, lane = tid & 63;
  const int quad = lane >> 4, l16 = lane & 15;
  const int bh = blockIdx.x;           // b*H + h
  const int b = bh >> 4, h = bh & 15;
  const int q0 = blockIdx.y * 128;
  const f16* Qbh = Q + ((size_t)bh * T_ + q0 + wave * 32) * HD_;
  const f16* Kbh = Km + (size_t)bh * T_ * HD_;
  const f16* Vbh = Vt + (size_t)bh * HD_ * T_;

  // persistent Q fragments (B-operand), two 16-row column blocks per wave
  f16x8 qf[2][2];
#pragma unroll
  for (int c = 0; c < 2; ++c) {
    qf[c][0] = *(const f16x8*)&Qbh[(c * 16 + l16) * HD_ + quad * 8];
    qf[c][1] = *(const f16x8*)&Qbh[(c * 16 + l16) * HD_ + 32 + quad * 8];
  }

  // hoisted per-lane staging pointers (advance by constant stride per tile)
  const f16* kq[4];
  const f16* vq[4];
  int lds_o[4];
#pragma unroll
  for (int it = 0; it < 4; ++it) {
    const int n = wave * 256 + it * 64 + lane;
    const int s = n >> 3, cp = n & 7, cl = cp ^ (s & 7);
    kq[it] = Kbh + (size_t)s * HD_ + cl * 8;
    const int d = n >> 4, cp2 = n & 15, cl2 = cp2 ^ (d & 7);
    vq[it] = Vbh + (size_t)d * T_ + cl2 * 8;
    lds_o[it] = (wave * 256 + it * 64) * 8;
  }

  f32x4 O[4][2] = {};      // ctx^T acc: [d-tile][q colblock]
  float lsum[2] = {0.f, 0.f};
  const int sw = l16 & 7;  // xor-swizzle key

  for (int kt = 0; kt < NT; ++kt) {
    __syncthreads();
#pragma unroll
    for (int it = 0; it < 4; ++it) {
      gl2lds16(kq[it], &Ks[lds_o[it]]);
      kq[it] += SK * HD_;
    }
#pragma unroll
    for (int it = 0; it < 4; ++it) {
      gl2lds16(vq[it], &Vs[lds_o[it]]);
      vq[it] += SK;
    }
    __syncthreads();

    // S^T = K Q^T: 8 key subtiles x 2 q colblocks; p = exp2(s) immediately
    float st[8][2][4];
#pragma unroll
    for (int s = 0; s < 8; ++s) {
      const int row = s * 16 + l16;
      const f16x8 ka = *(const f16x8*)&Ks[row * HD_ + (quad ^ sw) * 8];
      const f16x8 kb = *(const f16x8*)&Ks[row * HD_ + ((4 + quad) ^ sw) * 8];
#pragma unroll
      for (int c = 0; c < 2; ++c) {
        f32x4 a = {};
        a = __builtin_amdgcn_mfma_f32_16x16x32_f16(ka, qf[c][0], a, 0, 0, 0);
        a = __builtin_amdgcn_mfma_f32_16x16x32_f16(kb, qf[c][1], a, 0, 0, 0);
#pragma unroll
        for (int r = 0; r < 4; ++r) {
          st[s][c][r] = exp2f(a[r]);
          lsum[c] += st[s][c][r];
        }
      }
    }

    // PV: 4 chunks of 32 keys; P^T -> B-frag via per-wave LDS relayout
#pragma unroll
    for (int cI = 0; cI < 4; ++cI) {
#pragma unroll
      for (int c = 0; c < 2; ++c) {
        f16* pw = &Ps[wave][0];
        f16x4 w0, w1;
#pragma unroll
        for (int r = 0; r < 4; ++r) {
          w0[r] = (f16)st[2 * cI][c][r];
          w1[r] = (f16)st[2 * cI + 1][c][r];
        }
        *(f16x4*)&pw[l16 * 36 + quad * 4] = w0;       // key_local = quad*4..+3
        *(f16x4*)&pw[l16 * 36 + 16 + quad * 4] = w1;  // key_local = 16+quad*4..+3
        const f16x8 pf = *(const f16x8*)&pw[l16 * 36 + quad * 8];
#pragma unroll
        for (int dt = 0; dt < 4; ++dt) {
          const int d = dt * 16 + l16;
          const f16x8 vf = *(const f16x8*)&Vs[d * SK + (((cI * 4 + quad) ^ sw) * 8)];
          O[dt][c] = __builtin_amdgcn_mfma_f32_16x16x32_f16(vf, pf, O[dt][c], 0, 0, 0);
        }
      }
    }
  }

  // reduce softmax denom across quads; normalize; store
#pragma unroll
  for (int c = 0; c < 2; ++c) {
    float l = lsum[c];
    l += __shfl_xor(l, 16, 64);
    l += __shfl_xor(l, 32, 64);
    const float linv = 1.f / l;
    const int t = q0 + wave * 32 + c * 16 + l16;
#pragma unroll
    for (int dt = 0; dt < 4; ++dt) {
      f16x4 ov;
#pragma unroll
      for (int r = 0; r < 4; ++r) ov[r] = (f16)(O[dt][c][r] * linv);
      *(f16x4*)&ctx[((size_t)t * B_ + b) * D_ + h * HD_ + dt * 16 + quad * 4] = ov;
    }
  }
}

// ---------------------------------------------------------------- LayerNorm (input already has residual)
__global__ __launch_bounds__(256) void lnorm(const float* __restrict__ a,
                                             const float* __restrict__ g,
                                             const float* __restrict__ bb,
                                             float* __restrict__ out,
                                             f16* __restrict__ outh) {
  const int row = blockIdx.x, tid = threadIdx.x;
  const size_t base = (size_t)row * D_;
  float4 va = *(const float4*)&a[base + tid * 4];
  float x0 = va.x, x1 = va.y, x2 = va.z, x3 = va.w;
  float s = x0 + x1 + x2 + x3;
  float sq = x0 * x0 + x1 * x1 + x2 * x2 + x3 * x3;
#pragma unroll
  for (int off = 32; off; off >>= 1) {
    s += __shfl_down(s, off, 64);
    sq += __shfl_down(sq, off, 64);
  }
  __shared__ float rs[4], rq[4];
  __shared__ float mean_s, rstd_s;
  if ((tid & 63) == 0) { rs[tid >> 6] = s; rq[tid >> 6] = sq; }
  __syncthreads();
  if (tid == 0) {
    float S = rs[0] + rs[1] + rs[2] + rs[3];
    float Qq = rq[0] + rq[1] + rq[2] + rq[3];
    float mean = S / D_;
    float var = Qq / D_ - mean * mean;
    mean_s = mean;
    rstd_s = rsqrtf(var + 1e-5f);
  }
  __syncthreads();
  const float mean = mean_s, rstd = rstd_s;
  float4 vg = *(const float4*)&g[tid * 4];
  float4 vb = *(const float4*)&bb[tid * 4];
  float y0 = (x0 - mean) * rstd * vg.x + vb.x;
  float y1 = (x1 - mean) * rstd * vg.y + vb.y;
  float y2 = (x2 - mean) * rstd * vg.z + vb.z;
  float y3 = (x3 - mean) * rstd * vg.w + vb.w;
  *(float4*)&out[base + tid * 4] = make_float4(y0, y1, y2, y3);
  if (outh) {
    f16x4 o = {(f16)y0, (f16)y1, (f16)y2, (f16)y3};
    *(f16x4*)&outh[base + tid * 4] = o;
  }
}

// ---------------------------------------------------------------- launch
extern "C" void kernel_launch(void* const* d_in, const int* in_sizes, int n_in,
                              void* d_out, int out_size, void* d_ws, size_t ws_size,
                              hipStream_t stream) {
  const float* x  = (const float*)d_in[0];
  const float* Wq = (const float*)d_in[1];
  const float* bq = (const float*)d_in[2];
  const float* Wk = (const float*)d_in[3];
  const float* bk = (const float*)d_in[4];
  const float* Wv = (const float*)d_in[5];
  const float* bv = (const float*)d_in[6];
  const float* Wo = (const float*)d_in[7];
  const float* bo = (const float*)d_in[8];
  const float* Wl = (const float*)d_in[9];
  const float* bl = (const float*)d_in[10];
  const float* g1 = (const float*)d_in[11];
  const float* b1 = (const float*)d_in[12];
  const float* g2 = (const float*)d_in[13];
  const float* b2 = (const float*)d_in[14];

  char* ws = (char*)d_ws;
  const size_t MB = 1 << 20;
  f16*   xb   = (f16*)(ws + 0 * MB);
  f16*   wqkv = (f16*)(ws + 8 * MB);
  f16*   wob  = (f16*)(ws + 14 * MB);
  f16*   wlb  = (f16*)(ws + 16 * MB);
  float* bqkv = (float*)(ws + 18 * MB);
  f16*   qb   = (f16*)(ws + 19 * MB);
  f16*   kb   = (f16*)(ws + 27 * MB);
  f16*   vb   = (f16*)(ws + 35 * MB);
  f16*   ctxb = xb;
  float* att  = (float*)qb;          // 16MB spanning qb+kb
  f16*   hb   = vb;
  float* hbuf = (float*)ws;          // 16MB spanning xb+wqkv+wob (all dead by then)

  cvt_f32_f16<<<M_ * D_ / 1024, 256, 0, stream>>>(x, xb, M_ * D_);
  WPtrs wp;
  wp.s[0] = Wq; wp.s[1] = Wk; wp.s[2] = Wv; wp.s[3] = Wo; wp.s[4] = Wl;
  wp.d[0] = wqkv; wp.d[1] = wqkv + D_ * D_; wp.d[2] = wqkv + 2 * D_ * D_;
  wp.d[3] = wob; wp.d[4] = wlb;
  cvt5<<<5 * 1024, 256, 0, stream>>>(wp);
  bcat<<<3, 256, 0, stream>>>(bq, bk, bv, bqkv);

  gemm_qkv<<<dim3(3 * D_ / 128, M_ / 128), 256, 0, stream>>>(xb, wqkv, bqkv, qb, kb, vb);

  attn<<<dim3(B_ * H_, T_ / 128), 256, 0, stream>>>(qb, kb, vb, ctxb);

  dim3 gg(D_ / 64, M_ / 128);  // (16, 32) = 512 blocks, 2/CU
  // Wo GEMM with fused residual (+x)
  gemm_f16<<<gg, 256, 0, stream>>>(ctxb, wob, bo, x, att);
  lnorm<<<M_, 256, 0, stream>>>(att, g1, b1, hbuf, hb);
  // Wl GEMM with fused residual (+h)
  gemm_f16<<<gg, 256, 0, stream>>>(hb, wlb, bl, hbuf, att);
  lnorm<<<M_, 256, 0, stream>>>(att, g2, b2, (float*)d_out, nullptr);
}

// Round 8
// 238.830 us; speedup vs baseline: 1.0690x; 1.0486x over previous
//
#include <hip/hip_runtime.h>

#define T_ 1024
#define B_ 4
#define D_ 1024
#define H_ 16
#define HD_ 64
#define M_ (T_ * B_)  // 4096

typedef _Float16 f16;
typedef f16 f16x8 __attribute__((ext_vector_type(8)));
typedef f16 f16x4 __attribute__((ext_vector_type(4)));
typedef float f32x4 __attribute__((ext_vector_type(4)));

__device__ __forceinline__ void gl2lds16(const void* g, void* l) {
  __builtin_amdgcn_global_load_lds(
      (const __attribute__((address_space(1))) void*)g,
      (__attribute__((address_space(3))) void*)l, 16, 0, 0);
}

// ---------------------------------------------------------------- fused prep
// One kernel: cvt x (fp32->f16), cvt 5 weights, concat 3 qkv biases.
struct Prep {
  const float* x;
  const float* w[5];
  const float* b[3];
  f16* xd;
  f16* wd[5];
  float* bd;
};

__global__ __launch_bounds__(256) void prep(Prep p) {
  const int bid = blockIdx.x, tid = threadIdx.x;
  if (bid < 4096) {  // x: 4M elems
    const int i = bid * 1024 + tid * 4;
    float4 v = *(const float4*)(p.x + i);
    f16x4 o = {(f16)v.x, (f16)v.y, (f16)v.z, (f16)v.w};
    *(f16x4*)(p.xd + i) = o;
  } else if (bid < 9216) {  // 5 weights, 1M elems each
    const int wi = bid - 4096;
    const int a = wi >> 10;
    const int i = (wi & 1023) * 1024 + tid * 4;
    float4 v = *(const float4*)(p.w[a] + i);
    f16x4 o = {(f16)v.x, (f16)v.y, (f16)v.z, (f16)v.w};
    *(f16x4*)(p.wd[a] + i) = o;
  } else {  // 3 bias vectors -> bd[3072]
    const int j = bid - 9216;
    const int i = tid * 4;
    *(float4*)(p.bd + j * 1024 + i) = *(const float4*)(p.b[j] + i);
  }
}

// ---------------------------------------------------------------- GEMM 128x64 (BK=32)
// out[M,N] = (f16)(A @ W^T + bias + res); res/out are f16.
__global__ __launch_bounds__(256) void gemm_f16(const f16* __restrict__ A,
                                                const f16* __restrict__ W,
                                                const float* __restrict__ bias,
                                                const f16* __restrict__ res,
                                                f16* __restrict__ out) {
  constexpr int K = D_, BK = 32;
  __shared__ __align__(16) f16 As[128 * BK];
  __shared__ __align__(16) f16 Bs[64 * BK];
  const int tid = threadIdx.x;
  const int lane = tid & 63;
  const int quad = lane >> 4, l16 = lane & 15;
  const int m0 = blockIdx.y * 128, n0 = blockIdx.x * 64;
  const int wave = tid >> 6;
  const int wm = (wave >> 1) * 64, wn = (wave & 1) * 32;
  f32x4 acc[4][2] = {};
  for (int kt = 0; kt < K / BK; ++kt) {
    __syncthreads();
    const int kb = kt * BK;
#pragma unroll
    for (int i = 0; i < 2; ++i) {  // A-tile: 512 x 16B chunks
      const int c = i * 256 + tid;
      const int row = c >> 2, col8 = (c & 3) * 8;
      const int ldsbase = (i * 256 + (tid & ~63)) * 8;
      gl2lds16(A + (size_t)(m0 + row) * K + kb + col8, &As[ldsbase]);
    }
    {  // B-tile: 256 x 16B chunks
      const int row = tid >> 2, col8 = (tid & 3) * 8;
      const int ldsbase = (tid & ~63) * 8;
      gl2lds16(W + (size_t)(n0 + row) * K + kb + col8, &Bs[ldsbase]);
    }
    __syncthreads();
    f16x8 af[4], bf[2];
#pragma unroll
    for (int i = 0; i < 4; ++i)
      af[i] = *(const f16x8*)&As[(wm + i * 16 + l16) * BK + quad * 8];
#pragma unroll
    for (int j = 0; j < 2; ++j)
      bf[j] = *(const f16x8*)&Bs[(wn + j * 16 + l16) * BK + quad * 8];
#pragma unroll
    for (int i = 0; i < 4; ++i)
#pragma unroll
      for (int j = 0; j < 2; ++j)
        acc[i][j] = __builtin_amdgcn_mfma_f32_16x16x32_f16(af[i], bf[j], acc[i][j], 0, 0, 0);
  }
#pragma unroll
  for (int j = 0; j < 2; ++j) {
    const int n = n0 + wn + j * 16 + l16;
    const float bn = bias[n];
#pragma unroll
    for (int i = 0; i < 4; ++i) {
      const int m = m0 + wm + i * 16 + quad * 4;
#pragma unroll
      for (int r = 0; r < 4; ++r) {
        const float v = acc[i][j][r] + bn + (float)res[(size_t)(m + r) * D_ + n];
        out[(size_t)(m + r) * D_ + n] = (f16)v;
      }
    }
  }
}

// ---------------------------------------------------------------- fused QKV GEMM (BK=32)
// W = [3072, K] (q,k,v stacked); q (pre-scaled by 0.125*log2e), k -> [B,H,T,HD];
// v -> [B,H,HD,T]
#define QSCALE 0.18033688011112042f  // 0.125 * log2(e), folded into q
__global__ __launch_bounds__(256) void gemm_qkv(const f16* __restrict__ A,
                                                const f16* __restrict__ W,
                                                const float* __restrict__ bias,
                                                f16* __restrict__ qo,
                                                f16* __restrict__ ko,
                                                f16* __restrict__ vo) {
  constexpr int K = D_, BK = 32;
  __shared__ __align__(16) f16 As[128 * BK];
  __shared__ __align__(16) f16 Bs[128 * BK];
  const int tid = threadIdx.x;
  const int lane = tid & 63;
  const int quad = lane >> 4, l16 = lane & 15;
  const int m0 = blockIdx.y * 128, n0 = blockIdx.x * 128;
  const int wave = tid >> 6;
  const int wm = (wave >> 1) * 64, wn = (wave & 1) * 64;
  f32x4 acc[4][4] = {};
  for (int kt = 0; kt < K / BK; ++kt) {
    __syncthreads();
    const int kb = kt * BK;
#pragma unroll
    for (int i = 0; i < 2; ++i) {
      const int c = i * 256 + tid;
      const int row = c >> 2, col8 = (c & 3) * 8;
      const int ldsbase = (i * 256 + (tid & ~63)) * 8;
      gl2lds16(A + (size_t)(m0 + row) * K + kb + col8, &As[ldsbase]);
      gl2lds16(W + (size_t)(n0 + row) * K + kb + col8, &Bs[ldsbase]);
    }
    __syncthreads();
    f16x8 af[4], bf[4];
#pragma unroll
    for (int i = 0; i < 4; ++i)
      af[i] = *(const f16x8*)&As[(wm + i * 16 + l16) * BK + quad * 8];
#pragma unroll
    for (int j = 0; j < 4; ++j)
      bf[j] = *(const f16x8*)&Bs[(wn + j * 16 + l16) * BK + quad * 8];
#pragma unroll
    for (int i = 0; i < 4; ++i)
#pragma unroll
      for (int j = 0; j < 4; ++j)
        acc[i][j] = __builtin_amdgcn_mfma_f32_16x16x32_f16(af[i], bf[j], acc[i][j], 0, 0, 0);
  }
  const int which = n0 >> 10;  // block-uniform: 0=q 1=k 2=v
  f16* outp = which == 0 ? qo : (which == 1 ? ko : vo);
  const float sc = which == 0 ? QSCALE : 1.0f;
#pragma unroll
  for (int j = 0; j < 4; ++j) {
    const int n = n0 + wn + j * 16 + l16;
    const float bn = bias[n];
    const int nl = n & 1023;
    const int hh = nl >> 6, d = nl & 63;
#pragma unroll
    for (int i = 0; i < 4; ++i) {
#pragma unroll
      for (int r = 0; r < 4; ++r) {
        const int m = m0 + wm + i * 16 + quad * 4 + r;
        const float v = (acc[i][j][r] + bn) * sc;
        const int t = m >> 2, bb = m & 3;  // m = t*B + b
        if (which < 2)
          outp[((size_t)(bb * H_ + hh) * T_ + t) * HD_ + d] = (f16)v;
        else
          outp[((size_t)(bb * H_ + hh) * HD_ + d) * T_ + t] = (f16)v;
      }
    }
  }
}

// ---------------------------------------------------------------- attention
// Flash-style, no max subtraction (scores pre-scaled so p=exp2(s), |s| small).
// Q-tile 128 rows/block, 32 per wave. Grid (bh, qi): all 8 qi-blocks of one
// bh land on one XCD (flat%8 = bh%8) so K/V stay L2-resident (2MB/XCD).
// Q,K: [B,H,T,HD] fp16; V: [B,H,HD,T] fp16; ctx out: [T*B, D] fp16
__global__ __launch_bounds__(256) void attn(const f16* __restrict__ Q,
                                            const f16* __restrict__ Km,
                                            const f16* __restrict__ Vt,
                                            f16* __restrict__ ctx) {
  constexpr int SK = 128;      // keys per tile
  constexpr int NT = T_ / SK;  // 8 tiles
  __shared__ __align__(16) f16 Ks[SK * HD_];    // 16KB, xor-swizzled chunks
  __shared__ __align__(16) f16 Vs[HD_ * SK];    // 16KB, xor-swizzled chunks
  __shared__ __align__(16) f16 Ps[4][16 * 36];  // per-wave P^T relayout buffer
  const int tid = threadIdx.x, wave = tid >> 6, lane = tid & 63;
  const int quad = lane >> 4, l16 = lane & 15;
  const int bh = blockIdx.x;           // b*H + h
  const int b = bh >> 4, h = bh & 15;
  const int q0 = blockIdx.y * 128;
  const f16* Qbh = Q + ((size_t)bh * T_ + q0 + wave * 32) * HD_;
  const f16* Kbh = Km + (size_t)bh * T_ * HD_;
  const f16* Vbh = Vt + (size_t)bh * HD_ * T_;

  // persistent Q fragments (B-operand), two 16-row column blocks per wave
  f16x8 qf[2][2];
#pragma unroll
  for (int c = 0; c < 2; ++c) {
    qf[c][0] = *(const f16x8*)&Qbh[(c * 16 + l16) * HD_ + quad * 8];
    qf[c][1] = *(const f16x8*)&Qbh[(c * 16 + l16) * HD_ + 32 + quad * 8];
  }

  // hoisted per-lane staging pointers (advance by constant stride per tile)
  const f16* kq[4];
  const f16* vq[4];
  int lds_o[4];
#pragma unroll
  for (int it = 0; it < 4; ++it) {
    const int n = wave * 256 + it * 64 + lane;
    const int s = n >> 3, cp = n & 7, cl = cp ^ (s & 7);
    kq[it] = Kbh + (size_t)s * HD_ + cl * 8;
    const int d = n >> 4, cp2 = n & 15, cl2 = cp2 ^ (d & 7);
    vq[it] = Vbh + (size_t)d * T_ + cl2 * 8;
    lds_o[it] = (wave * 256 + it * 64) * 8;
  }

  f32x4 O[4][2] = {};      // ctx^T acc: [d-tile][q colblock]
  float lsum[2] = {0.f, 0.f};
  const int sw = l16 & 7;  // xor-swizzle key

  for (int kt = 0; kt < NT; ++kt) {
    __syncthreads();
#pragma unroll
    for (int it = 0; it < 4; ++it) {
      gl2lds16(kq[it], &Ks[lds_o[it]]);
      kq[it] += SK * HD_;
    }
#pragma unroll
    for (int it = 0; it < 4; ++it) {
      gl2lds16(vq[it], &Vs[lds_o[it]]);
      vq[it] += SK;
    }
    __syncthreads();

    // S^T = K Q^T: 8 key subtiles x 2 q colblocks; p = exp2(s) immediately
    float st[8][2][4];
#pragma unroll
    for (int s = 0; s < 8; ++s) {
      const int row = s * 16 + l16;
      const f16x8 ka = *(const f16x8*)&Ks[row * HD_ + (quad ^ sw) * 8];
      const f16x8 kb = *(const f16x8*)&Ks[row * HD_ + ((4 + quad) ^ sw) * 8];
#pragma unroll
      for (int c = 0; c < 2; ++c) {
        f32x4 a = {};
        a = __builtin_amdgcn_mfma_f32_16x16x32_f16(ka, qf[c][0], a, 0, 0, 0);
        a = __builtin_amdgcn_mfma_f32_16x16x32_f16(kb, qf[c][1], a, 0, 0, 0);
#pragma unroll
        for (int r = 0; r < 4; ++r) {
          st[s][c][r] = exp2f(a[r]);
          lsum[c] += st[s][c][r];
        }
      }
    }

    // PV: 4 chunks of 32 keys; P^T -> B-frag via per-wave LDS relayout
#pragma unroll
    for (int cI = 0; cI < 4; ++cI) {
#pragma unroll
      for (int c = 0; c < 2; ++c) {
        f16* pw = &Ps[wave][0];
        f16x4 w0, w1;
#pragma unroll
        for (int r = 0; r < 4; ++r) {
          w0[r] = (f16)st[2 * cI][c][r];
          w1[r] = (f16)st[2 * cI + 1][c][r];
        }
        *(f16x4*)&pw[l16 * 36 + quad * 4] = w0;       // key_local = quad*4..+3
        *(f16x4*)&pw[l16 * 36 + 16 + quad * 4] = w1;  // key_local = 16+quad*4..+3
        const f16x8 pf = *(const f16x8*)&pw[l16 * 36 + quad * 8];
#pragma unroll
        for (int dt = 0; dt < 4; ++dt) {
          const int d = dt * 16 + l16;
          const f16x8 vf = *(const f16x8*)&Vs[d * SK + (((cI * 4 + quad) ^ sw) * 8)];
          O[dt][c] = __builtin_amdgcn_mfma_f32_16x16x32_f16(vf, pf, O[dt][c], 0, 0, 0);
        }
      }
    }
  }

  // reduce softmax denom across quads; normalize; store
#pragma unroll
  for (int c = 0; c < 2; ++c) {
    float l = lsum[c];
    l += __shfl_xor(l, 16, 64);
    l += __shfl_xor(l, 32, 64);
    const float linv = 1.f / l;
    const int t = q0 + wave * 32 + c * 16 + l16;
#pragma unroll
    for (int dt = 0; dt < 4; ++dt) {
      f16x4 ov;
#pragma unroll
      for (int r = 0; r < 4; ++r) ov[r] = (f16)(O[dt][c][r] * linv);
      *(f16x4*)&ctx[((size_t)t * B_ + b) * D_ + h * HD_ + dt * 16 + quad * 4] = ov;
    }
  }
}

// ---------------------------------------------------------------- LayerNorm
// input f16 (already has residual); writes f16 (outh) and/or fp32 (outf).
__global__ __launch_bounds__(256) void lnorm(const f16* __restrict__ a,
                                             const float* __restrict__ g,
                                             const float* __restrict__ bb,
                                             f16* __restrict__ outh,
                                             float* __restrict__ outf) {
  const int row = blockIdx.x, tid = threadIdx.x;
  const size_t base = (size_t)row * D_;
  f16x4 va = *(const f16x4*)&a[base + tid * 4];
  float x0 = (float)va[0], x1 = (float)va[1], x2 = (float)va[2], x3 = (float)va[3];
  float s = x0 + x1 + x2 + x3;
  float sq = x0 * x0 + x1 * x1 + x2 * x2 + x3 * x3;
#pragma unroll
  for (int off = 32; off; off >>= 1) {
    s += __shfl_down(s, off, 64);
    sq += __shfl_down(sq, off, 64);
  }
  __shared__ float rs[4], rq[4];
  __shared__ float mean_s, rstd_s;
  if ((tid & 63) == 0) { rs[tid >> 6] = s; rq[tid >> 6] = sq; }
  __syncthreads();
  if (tid == 0) {
    float S = rs[0] + rs[1] + rs[2] + rs[3];
    float Qq = rq[0] + rq[1] + rq[2] + rq[3];
    float mean = S / D_;
    float var = Qq / D_ - mean * mean;
    mean_s = mean;
    rstd_s = rsqrtf(var + 1e-5f);
  }
  __syncthreads();
  const float mean = mean_s, rstd = rstd_s;
  float4 vg = *(const float4*)&g[tid * 4];
  float4 vb = *(const float4*)&bb[tid * 4];
  float y0 = (x0 - mean) * rstd * vg.x + vb.x;
  float y1 = (x1 - mean) * rstd * vg.y + vb.y;
  float y2 = (x2 - mean) * rstd * vg.z + vb.z;
  float y3 = (x3 - mean) * rstd * vg.w + vb.w;
  if (outh) {
    f16x4 o = {(f16)y0, (f16)y1, (f16)y2, (f16)y3};
    *(f16x4*)&outh[base + tid * 4] = o;
  }
  if (outf)
    *(float4*)&outf[base + tid * 4] = make_float4(y0, y1, y2, y3);
}

// ---------------------------------------------------------------- launch
extern "C" void kernel_launch(void* const* d_in, const int* in_sizes, int n_in,
                              void* d_out, int out_size, void* d_ws, size_t ws_size,
                              hipStream_t stream) {
  const float* x  = (const float*)d_in[0];
  const float* Wq = (const float*)d_in[1];
  const float* bq = (const float*)d_in[2];
  const float* Wk = (const float*)d_in[3];
  const float* bk = (const float*)d_in[4];
  const float* Wv = (const float*)d_in[5];
  const float* bv = (const float*)d_in[6];
  const float* Wo = (const float*)d_in[7];
  const float* bo = (const float*)d_in[8];
  const float* Wl = (const float*)d_in[9];
  const float* bl = (const float*)d_in[10];
  const float* g1 = (const float*)d_in[11];
  const float* b1 = (const float*)d_in[12];
  const float* g2 = (const float*)d_in[13];
  const float* b2 = (const float*)d_in[14];

  char* ws = (char*)d_ws;
  const size_t MB = 1 << 20;
  // layout (51MB): xb stays alive as f16 residual for Wo GEMM.
  f16*   xb   = (f16*)(ws + 0 * MB);    // 8MB
  f16*   wqkv = (f16*)(ws + 8 * MB);    // 6MB
  f16*   wob  = (f16*)(ws + 14 * MB);   // 2MB
  f16*   wlb  = (f16*)(ws + 16 * MB);   // 2MB
  float* bqkv = (float*)(ws + 18 * MB); // 12KB
  f16*   qb   = (f16*)(ws + 19 * MB);   // 8MB -> att (f16) after attn
  f16*   kb   = (f16*)(ws + 27 * MB);   // 8MB -> hbuf (f16) after attn
  f16*   vb   = (f16*)(ws + 35 * MB);   // 8MB
  f16*   ctxb = (f16*)(ws + 43 * MB);   // 8MB
  f16*   att  = qb;
  f16*   hbuf = kb;

  Prep p;
  p.x = x;
  p.w[0] = Wq; p.w[1] = Wk; p.w[2] = Wv; p.w[3] = Wo; p.w[4] = Wl;
  p.b[0] = bq; p.b[1] = bk; p.b[2] = bv;
  p.xd = xb;
  p.wd[0] = wqkv; p.wd[1] = wqkv + D_ * D_; p.wd[2] = wqkv + 2 * D_ * D_;
  p.wd[3] = wob; p.wd[4] = wlb;
  p.bd = bqkv;
  prep<<<9219, 256, 0, stream>>>(p);

  gemm_qkv<<<dim3(3 * D_ / 128, M_ / 128), 256, 0, stream>>>(xb, wqkv, bqkv, qb, kb, vb);

  attn<<<dim3(B_ * H_, T_ / 128), 256, 0, stream>>>(qb, kb, vb, ctxb);

  dim3 gg(D_ / 64, M_ / 128);  // (16, 32) = 512 blocks, 2/CU
  // Wo GEMM with fused residual (+x, f16)
  gemm_f16<<<gg, 256, 0, stream>>>(ctxb, wob, bo, xb, att);
  lnorm<<<M_, 256, 0, stream>>>(att, g1, b1, hbuf, nullptr);
  // Wl GEMM with fused residual (+h)
  gemm_f16<<<gg, 256, 0, stream>>>(hbuf, wlb, bl, hbuf, att);
  lnorm<<<M_, 256, 0, stream>>>(att, g2, b2, nullptr, (float*)d_out);
}